// Round 2
// baseline (436.932 us; speedup 1.0000x reference)
//
#include <hip/hip_runtime.h>
#include <hip/hip_cooperative_groups.h>
#include <math.h>

namespace cg = cooperative_groups;

#define N_NODES 20000
#define N_EDGES 320000
#define EMB 256
#define NUM_TILES ((N_NODES + 255) / 256)  // 79
#define GRID_FUSED 625                     // = N_NODES/32 gemm tiles
#define NTHR_FUSED (GRID_FUSED * 256)      // 160000
#define LDS_PITCH 264                      // 256 + 8 shorts: breaks bank-stride, keeps 16B align

typedef __attribute__((ext_vector_type(8))) short short8;
typedef __attribute__((ext_vector_type(4))) float floatx4;

__device__ __forceinline__ unsigned short bf16r(float x) {
    unsigned u = __float_as_uint(x);
    u += 0x7fffu + ((u >> 16) & 1u);
    return (unsigned short)(u >> 16);
}

// ---------------------------------------------------------------------------
// Shared GEMM tile body: S = h @ W_self^T for 32 rows; packed[n][c] =
// (bf16(exp(S)), bf16(h)).  Epilogue stores DIRECTLY from acc in C/D layout
// (col=lane&15, row=(lane>>4)*4+reg — verified mapping from the 178µs kernel);
// per (mt,nt,r) a wave writes 4 aligned 64B segments, all bytes useful.
// No Et buffer -> LDS/block 18.9KB -> coop validator allows 3 blocks/CU.
// ---------------------------------------------------------------------------
__device__ __forceinline__ void gemm_tile(
        const float* __restrict__ h, const unsigned short* __restrict__ Wb,
        unsigned int* __restrict__ packed, unsigned short (*At)[LDS_PITCH],
        int b, int t) {
    int w = t >> 6, l = t & 63;
    int m0 = b * 32;
    int n0 = w * 64;
    int lm = l & 15, lk = (l >> 4) * 8;

    // stage A: 32 rows x 256 cols fp32 -> bf16 LDS, coalesced float4 reads
#pragma unroll
    for (int it = 0; it < 8; ++it) {
        int q = it * 256 + t;            // [0, 2048)
        int row = q >> 6;                // 64 float4 per row
        int c4 = (q & 63) * 4;
        float4 x = *(const float4*)(h + (size_t)(m0 + row) * EMB + c4);
        At[row][c4 + 0] = bf16r(x.x);
        At[row][c4 + 1] = bf16r(x.y);
        At[row][c4 + 2] = bf16r(x.z);
        At[row][c4 + 3] = bf16r(x.w);
    }
    __syncthreads();

    floatx4 acc[2][4];
#pragma unroll
    for (int mt = 0; mt < 2; ++mt)
#pragma unroll
        for (int nt = 0; nt < 4; ++nt) acc[mt][nt] = (floatx4){0.f, 0.f, 0.f, 0.f};

    const unsigned short* a0p = &At[lm][lk];
    const unsigned short* a1p = &At[16 + lm][lk];
    const unsigned short* bp = Wb + (size_t)(n0 + lm) * EMB + lk;

#pragma unroll
    for (int k0 = 0; k0 < EMB; k0 += 32) {
        short8 a0 = *(const short8*)(a0p + k0);
        short8 a1 = *(const short8*)(a1p + k0);
        short8 b0 = *(const short8*)(bp + k0);
        short8 b1 = *(const short8*)(bp + 16 * EMB + k0);
        short8 b2 = *(const short8*)(bp + 32 * EMB + k0);
        short8 b3 = *(const short8*)(bp + 48 * EMB + k0);
        acc[0][0] = __builtin_amdgcn_mfma_f32_16x16x32_bf16(a0, b0, acc[0][0], 0, 0, 0);
        acc[0][1] = __builtin_amdgcn_mfma_f32_16x16x32_bf16(a0, b1, acc[0][1], 0, 0, 0);
        acc[0][2] = __builtin_amdgcn_mfma_f32_16x16x32_bf16(a0, b2, acc[0][2], 0, 0, 0);
        acc[0][3] = __builtin_amdgcn_mfma_f32_16x16x32_bf16(a0, b3, acc[0][3], 0, 0, 0);
        acc[1][0] = __builtin_amdgcn_mfma_f32_16x16x32_bf16(a1, b0, acc[1][0], 0, 0, 0);
        acc[1][1] = __builtin_amdgcn_mfma_f32_16x16x32_bf16(a1, b1, acc[1][1], 0, 0, 0);
        acc[1][2] = __builtin_amdgcn_mfma_f32_16x16x32_bf16(a1, b2, acc[1][2], 0, 0, 0);
        acc[1][3] = __builtin_amdgcn_mfma_f32_16x16x32_bf16(a1, b3, acc[1][3], 0, 0, 0);
    }

    // direct epilogue: per element read bf16(h) partner from At, store packed
#pragma unroll
    for (int mt = 0; mt < 2; ++mt)
#pragma unroll
        for (int nt = 0; nt < 4; ++nt) {
            int col = n0 + nt * 16 + lm;
#pragma unroll
            for (int r = 0; r < 4; ++r) {
                int row = mt * 16 + (l >> 4) * 4 + r;
                unsigned u = (unsigned)bf16r(__expf(acc[mt][nt][r])) |
                             ((unsigned)At[row][col] << 16);
                packed[(size_t)(m0 + row) * EMB + col] = u;
            }
        }
}

// ---------------------------------------------------------------------------
// Fused cooperative kernel: zero+Wconv -> degree count -> tile sums -> CSR
// scan -> (gemm tile || scatter).  One dispatch replaces 6 (incl. memset).
// LDS = At(16.9K) + red(1K) + sc(1K) = 18.9KB -> 3 blocks/CU under the
// runtime's 64KB coop-occupancy accounting -> max grid 768 >= 625.
// ---------------------------------------------------------------------------
__global__ __launch_bounds__(256, 3) void fused_kernel(
        const float* __restrict__ h, const float* __restrict__ W,
        const int* __restrict__ src, const int* __restrict__ dst,
        unsigned int* __restrict__ packed, unsigned short* __restrict__ Wb,
        int* __restrict__ deg, int* __restrict__ row_start,
        int* __restrict__ cursor, int* __restrict__ tile_sums,
        int* __restrict__ csr_src) {
    cg::grid_group grid = cg::this_grid();
    __shared__ unsigned short At[32][LDS_PITCH];
    __shared__ int red[256];
    __shared__ int sc[256];

    const int b = blockIdx.x, t = threadIdx.x;
    const int gid = b * 256 + t;

    // ---- P0: zero degrees + convert W_self to bf16 ----
    for (int i = gid; i < N_NODES; i += NTHR_FUSED) deg[i] = 0;
    if (gid < (EMB * EMB) / 8) {
        long off = (long)gid * 8;
        float4 x = *(const float4*)(W + off);
        float4 y = *(const float4*)(W + off + 4);
        uint4 o;
        o.x = (unsigned)bf16r(x.x) | ((unsigned)bf16r(x.y) << 16);
        o.y = (unsigned)bf16r(x.z) | ((unsigned)bf16r(x.w) << 16);
        o.z = (unsigned)bf16r(y.x) | ((unsigned)bf16r(y.y) << 16);
        o.w = (unsigned)bf16r(y.z) | ((unsigned)bf16r(y.w) << 16);
        *(uint4*)(Wb + off) = o;
    }
    grid.sync();

    // ---- P1: degree count ----
    for (int i = gid; i < N_EDGES; i += NTHR_FUSED) atomicAdd(&deg[dst[i]], 1);
    grid.sync();

    // ---- P2: per-tile sums (blocks 0..78) ----
    if (b < NUM_TILES) {
        int i = b * 256 + t;
        red[t] = (i < N_NODES) ? deg[i] : 0;
        __syncthreads();
#pragma unroll
        for (int off = 128; off > 0; off >>= 1) {
            if (t < off) red[t] += red[t + off];
            __syncthreads();
        }
        if (t == 0) tile_sums[b] = red[0];
    }
    grid.sync();

    // ---- P3: CSR exclusive scan (blocks 0..78) ----
    if (b < NUM_TILES) {
        int i = b * 256 + t;
        int v = (i < N_NODES) ? deg[i] : 0;
        red[t] = (t < b) ? tile_sums[t] : 0;  // b <= 78 < 256
        sc[t] = v;
        __syncthreads();
#pragma unroll
        for (int off = 128; off > 0; off >>= 1) {
            if (t < off) red[t] += red[t + off];
            __syncthreads();
        }
        int base = red[0];
#pragma unroll
        for (int off = 1; off < 256; off <<= 1) {
            int tmp = (t >= off) ? sc[t - off] : 0;
            __syncthreads();
            sc[t] += tmp;
            __syncthreads();
        }
        int excl = base + sc[t] - v;
        if (i < N_NODES) {
            row_start[i] = excl;
            cursor[i] = excl;
        }
        if (i == N_NODES - 1) row_start[N_NODES] = excl + v;
    }
    grid.sync();

    // ---- P4: gemm tile b (independent of CSR) + scatter (needs cursor) ----
    gemm_tile(h, Wb, packed, At, b, t);
    for (int i = gid; i < N_EDGES; i += NTHR_FUSED) {
        int d = dst[i];
        int pos = atomicAdd(&cursor[d], 1);
        csr_src[pos] = src[i];
    }
}

// ---------------------------------------------------------------------------
// Fallback pipeline (engaged only if cooperative launch returns an error)
// ---------------------------------------------------------------------------
__global__ __launch_bounds__(256) void prep_kernel(
        const float* __restrict__ W, const int* __restrict__ dst,
        int* __restrict__ deg, unsigned short* __restrict__ Wb) {
    int gid = blockIdx.x * 256 + threadIdx.x;
    if (gid < N_EDGES) atomicAdd(&deg[dst[gid]], 1);
    if (gid < (EMB * EMB) / 8) {
        long off = (long)gid * 8;
        float4 x = *(const float4*)(W + off);
        float4 y = *(const float4*)(W + off + 4);
        uint4 o;
        o.x = (unsigned)bf16r(x.x) | ((unsigned)bf16r(x.y) << 16);
        o.y = (unsigned)bf16r(x.z) | ((unsigned)bf16r(x.w) << 16);
        o.z = (unsigned)bf16r(y.x) | ((unsigned)bf16r(y.y) << 16);
        o.w = (unsigned)bf16r(y.z) | ((unsigned)bf16r(y.w) << 16);
        *(uint4*)(Wb + off) = o;
    }
}

__global__ __launch_bounds__(256) void tilesum_kernel(const int* __restrict__ deg,
                                                      int* __restrict__ tile_sums) {
    __shared__ int red[256];
    int t = threadIdx.x;
    int i = blockIdx.x * 256 + t;
    red[t] = (i < N_NODES) ? deg[i] : 0;
    __syncthreads();
#pragma unroll
    for (int off = 128; off > 0; off >>= 1) {
        if (t < off) red[t] += red[t + off];
        __syncthreads();
    }
    if (t == 0) tile_sums[blockIdx.x] = red[0];
}

__global__ __launch_bounds__(256) void csr_kernel(const int* __restrict__ deg,
                                                  const int* __restrict__ tile_sums,
                                                  int* __restrict__ row_start,
                                                  int* __restrict__ cursor) {
    __shared__ int redb[256];
    __shared__ int sc[256];
    int b = blockIdx.x, t = threadIdx.x;
    int i = b * 256 + t;
    int v = (i < N_NODES) ? deg[i] : 0;
    redb[t] = (t < b) ? tile_sums[t] : 0;
    sc[t] = v;
    __syncthreads();
#pragma unroll
    for (int off = 128; off > 0; off >>= 1) {
        if (t < off) redb[t] += redb[t + off];
        __syncthreads();
    }
    int base = redb[0];
#pragma unroll
    for (int off = 1; off < 256; off <<= 1) {
        int tmp = (t >= off) ? sc[t - off] : 0;
        __syncthreads();
        sc[t] += tmp;
        __syncthreads();
    }
    int excl = base + sc[t] - v;
    if (i < N_NODES) {
        row_start[i] = excl;
        cursor[i] = excl;
    }
    if (i == N_NODES - 1) row_start[N_NODES] = excl + v;
}

__global__ void scatter_kernel(const int* __restrict__ src, const int* __restrict__ dst,
                               int* __restrict__ cursor, int* __restrict__ csr_src, int n) {
    int i = blockIdx.x * blockDim.x + threadIdx.x;
    if (i < n) {
        int d = dst[i];
        int pos = atomicAdd(&cursor[d], 1);
        csr_src[pos] = src[i];
    }
}

__global__ __launch_bounds__(256) void gemm_kernel(
        const float* __restrict__ h, const unsigned short* __restrict__ Wb,
        unsigned int* __restrict__ packed) {
    __shared__ unsigned short At[32][LDS_PITCH];
    gemm_tile(h, Wb, packed, At, blockIdx.x, threadIdx.x);
}

// ---------- aggregate: one wave per node, single pass ----------
#define PROC(p)                                                                  \
    {                                                                            \
        unsigned u;                                                              \
        float e, hv;                                                             \
        u = (p).x; e = __uint_as_float(u << 16);                                 \
        hv = __uint_as_float(u & 0xffff0000u); ss0 += e; a0 = fmaf(e, hv, a0);   \
        u = (p).y; e = __uint_as_float(u << 16);                                 \
        hv = __uint_as_float(u & 0xffff0000u); ss1 += e; a1 = fmaf(e, hv, a1);   \
        u = (p).z; e = __uint_as_float(u << 16);                                 \
        hv = __uint_as_float(u & 0xffff0000u); ss2 += e; a2 = fmaf(e, hv, a2);   \
        u = (p).w; e = __uint_as_float(u << 16);                                 \
        hv = __uint_as_float(u & 0xffff0000u); ss3 += e; a3 = fmaf(e, hv, a3);   \
    }

__global__ __launch_bounds__(256) void aggregate_kernel(
        const float* __restrict__ h, const uint4* __restrict__ packed,
        const int* __restrict__ row_start, const int* __restrict__ csr_src,
        float* __restrict__ out) {
    int w = threadIdx.x >> 6, l = threadIdx.x & 63;
    int node = blockIdx.x * 4 + w;
    int start = row_start[node], end = row_start[node + 1];
    if (start == end) {  // zero in-degree: pass through h
        float4 v = *(const float4*)(h + (size_t)node * EMB + l * 4);
        *(float4*)(out + (size_t)node * EMB + l * 4) = v;
        return;
    }
    float ss0 = 0.f, ss1 = 0.f, ss2 = 0.f, ss3 = 0.f;
    float a0 = 0.f, a1 = 0.f, a2 = 0.f, a3 = 0.f;
    for (int base = start; base < end; base += 64) {
        int cnt = min(64, end - base);
        int sv = (l < cnt) ? csr_src[base + l] : 0;
        int i = 0;
        for (; i + 8 <= cnt; i += 8) {
            int s0 = __shfl(sv, i),     s1 = __shfl(sv, i + 1);
            int s2 = __shfl(sv, i + 2), s3 = __shfl(sv, i + 3);
            int s4 = __shfl(sv, i + 4), s5 = __shfl(sv, i + 5);
            int s6 = __shfl(sv, i + 6), s7 = __shfl(sv, i + 7);
            uint4 p0 = packed[(size_t)s0 * 64 + l];
            uint4 p1 = packed[(size_t)s1 * 64 + l];
            uint4 p2 = packed[(size_t)s2 * 64 + l];
            uint4 p3 = packed[(size_t)s3 * 64 + l];
            uint4 p4 = packed[(size_t)s4 * 64 + l];
            uint4 p5 = packed[(size_t)s5 * 64 + l];
            uint4 p6 = packed[(size_t)s6 * 64 + l];
            uint4 p7 = packed[(size_t)s7 * 64 + l];
            PROC(p0); PROC(p1); PROC(p2); PROC(p3);
            PROC(p4); PROC(p5); PROC(p6); PROC(p7);
        }
        // tail: wave-uniform predicated batch — all remaining loads in flight
        int r = cnt - i;
        if (r > 0) {
            int s0 = __shfl(sv, i);
            uint4 p0 = packed[(size_t)s0 * 64 + l];
            uint4 p1, p2, p3, p4, p5, p6;
            if (r > 1) { int s = __shfl(sv, i + 1); p1 = packed[(size_t)s * 64 + l]; }
            if (r > 2) { int s = __shfl(sv, i + 2); p2 = packed[(size_t)s * 64 + l]; }
            if (r > 3) { int s = __shfl(sv, i + 3); p3 = packed[(size_t)s * 64 + l]; }
            if (r > 4) { int s = __shfl(sv, i + 4); p4 = packed[(size_t)s * 64 + l]; }
            if (r > 5) { int s = __shfl(sv, i + 5); p5 = packed[(size_t)s * 64 + l]; }
            if (r > 6) { int s = __shfl(sv, i + 6); p6 = packed[(size_t)s * 64 + l]; }
            PROC(p0);
            if (r > 1) PROC(p1);
            if (r > 2) PROC(p2);
            if (r > 3) PROC(p3);
            if (r > 4) PROC(p4);
            if (r > 5) PROC(p5);
            if (r > 6) PROC(p6);
        }
    }
    float4 o;
    o.x = a0 / ss0; o.y = a1 / ss1; o.z = a2 / ss2; o.w = a3 / ss3;
    *(float4*)(out + (size_t)node * EMB + l * 4) = o;
}

// ---------- launch ----------
extern "C" void kernel_launch(void* const* d_in, const int* in_sizes, int n_in,
                              void* d_out, int out_size, void* d_ws, size_t ws_size,
                              hipStream_t stream) {
    const float* h      = (const float*)d_in[0];
    // W_nb (d_in[1]), b_nb (d_in[2]), b_self (d_in[4]) are mathematically
    // irrelevant: constant per (dst, channel) inside each softmax segment,
    // cancel exactly in alpha = e / seg_sum.
    const float* W_self = (const float*)d_in[3];
    const int*   src    = (const int*)d_in[5];
    const int*   dst    = (const int*)d_in[6];
    float* out = (float*)d_out;

    char* ws = (char*)d_ws;
    unsigned int* packed = (unsigned int*)ws;                 // [N,256] uint (E,h) pairs
    size_t off = (size_t)N_NODES * EMB * sizeof(unsigned int);
    unsigned short* Wb = (unsigned short*)(ws + off); off += (size_t)EMB * EMB * sizeof(unsigned short);
    int* deg       = (int*)(ws + off); off += (size_t)N_NODES * sizeof(int);
    int* row_start = (int*)(ws + off); off += (size_t)(N_NODES + 1) * sizeof(int);
    int* cursor    = (int*)(ws + off); off += (size_t)N_NODES * sizeof(int);
    int* tile_sums = (int*)(ws + off); off += (size_t)NUM_TILES * sizeof(int);
    int* csr_src   = (int*)(ws + off); off += (size_t)N_EDGES * sizeof(int);

    void* args[] = {(void*)&h, (void*)&W_self, (void*)&src, (void*)&dst,
                    (void*)&packed, (void*)&Wb, (void*)&deg, (void*)&row_start,
                    (void*)&cursor, (void*)&tile_sums, (void*)&csr_src};
    hipError_t cerr = hipLaunchCooperativeKernel((const void*)fused_kernel,
                                                 dim3(GRID_FUSED), dim3(256), args,
                                                 0, stream);
    if (cerr != hipSuccess) {
        // fallback: proven 6-dispatch pipeline
        (void)hipMemsetAsync(deg, 0, (size_t)N_NODES * sizeof(int), stream);
        prep_kernel<<<(N_EDGES + 255) / 256, 256, 0, stream>>>(W_self, dst, deg, Wb);
        tilesum_kernel<<<NUM_TILES, 256, 0, stream>>>(deg, tile_sums);
        csr_kernel<<<NUM_TILES, 256, 0, stream>>>(deg, tile_sums, row_start, cursor);
        scatter_kernel<<<(N_EDGES + 255) / 256, 256, 0, stream>>>(src, dst, cursor,
                                                                  csr_src, N_EDGES);
        gemm_kernel<<<N_NODES / 32, 256, 0, stream>>>(h, Wb, packed);
    }
    aggregate_kernel<<<N_NODES / 4, 256, 0, stream>>>(h, (const uint4*)packed,
                                                      row_start, csr_src, out);
}

// Round 3
// 175.564 us; speedup vs baseline: 2.4887x; 2.4887x over previous
//
#include <hip/hip_runtime.h>
#include <math.h>

#define N_NODES 20000
#define N_EDGES 320000
#define EMB 256
#define GEMM_BLOCKS (N_NODES / 32)         // 625
#define SCAT_BLOCKS ((N_EDGES + 255) / 256) // 1250
#define LDS_PITCH 264                      // 256 + 8 shorts: breaks bank-stride, keeps 16B align

typedef __attribute__((ext_vector_type(8))) short short8;
typedef __attribute__((ext_vector_type(4))) float floatx4;

__device__ __forceinline__ unsigned short bf16r(float x) {
    unsigned u = __float_as_uint(x);
    u += 0x7fffu + ((u >> 16) & 1u);
    return (unsigned short)(u >> 16);
}

// ---------- prep: count degrees + convert W_self to bf16 ----------
__global__ __launch_bounds__(256) void prep_kernel(
        const float* __restrict__ W, const int* __restrict__ dst,
        int* __restrict__ deg, unsigned short* __restrict__ Wb) {
    int gid = blockIdx.x * 256 + threadIdx.x;
    if (gid < N_EDGES) atomicAdd(&deg[dst[gid]], 1);
    if (gid < (EMB * EMB) / 8) {
        long off = (long)gid * 8;
        float4 x = *(const float4*)(W + off);
        float4 y = *(const float4*)(W + off + 4);
        uint4 o;
        o.x = (unsigned)bf16r(x.x) | ((unsigned)bf16r(x.y) << 16);
        o.y = (unsigned)bf16r(x.z) | ((unsigned)bf16r(x.w) << 16);
        o.z = (unsigned)bf16r(y.x) | ((unsigned)bf16r(y.y) << 16);
        o.w = (unsigned)bf16r(y.z) | ((unsigned)bf16r(y.w) << 16);
        *(uint4*)(Wb + off) = o;
    }
}

// ---------- alloc: segment base per node via wave-scan + 1 atomic/wave ----------
// Segments need NOT be in node order (sums are order-independent), so the
// two-kernel tile-scan is replaced by a single kernel: 64-lane shfl prefix
// sum of degrees, one atomicAdd on a global counter per wave (313 total).
__global__ __launch_bounds__(256) void alloc_kernel(
        const int* __restrict__ deg, int* __restrict__ total,
        int* __restrict__ row_start, int* __restrict__ cursor) {
    int i = blockIdx.x * 256 + threadIdx.x;
    int l = threadIdx.x & 63;
    int v = (i < N_NODES) ? deg[i] : 0;
    int s = v;  // inclusive wave scan
#pragma unroll
    for (int off = 1; off < 64; off <<= 1) {
        int u = __shfl_up(s, off);
        if (l >= off) s += u;
    }
    int waveTotal = __shfl(s, 63);
    int base = 0;
    if (l == 63) base = atomicAdd(total, waveTotal);
    base = __shfl(base, 63);
    int excl = base + s - v;
    if (i < N_NODES) {
        row_start[i] = excl;
        cursor[i] = excl;
    }
}

// ---------------------------------------------------------------------------
// GEMM tile body: S = h @ W_self^T for 32 rows; packed[n][c] =
// (bf16(exp(S)), bf16(h)).  Direct epilogue from acc in C/D layout
// (col=lane&15, row=(lane>>4)*4+reg) — harness-verified in R2.
// ---------------------------------------------------------------------------
__device__ __forceinline__ void gemm_tile(
        const float* __restrict__ h, const unsigned short* __restrict__ Wb,
        unsigned int* __restrict__ packed, unsigned short (*At)[LDS_PITCH],
        int b, int t) {
    int w = t >> 6, l = t & 63;
    int m0 = b * 32;
    int n0 = w * 64;
    int lm = l & 15, lk = (l >> 4) * 8;

    // stage A: 32 rows x 256 cols fp32 -> bf16 LDS, coalesced float4 reads
#pragma unroll
    for (int it = 0; it < 8; ++it) {
        int q = it * 256 + t;            // [0, 2048)
        int row = q >> 6;                // 64 float4 per row
        int c4 = (q & 63) * 4;
        float4 x = *(const float4*)(h + (size_t)(m0 + row) * EMB + c4);
        At[row][c4 + 0] = bf16r(x.x);
        At[row][c4 + 1] = bf16r(x.y);
        At[row][c4 + 2] = bf16r(x.z);
        At[row][c4 + 3] = bf16r(x.w);
    }
    __syncthreads();

    floatx4 acc[2][4];
#pragma unroll
    for (int mt = 0; mt < 2; ++mt)
#pragma unroll
        for (int nt = 0; nt < 4; ++nt) acc[mt][nt] = (floatx4){0.f, 0.f, 0.f, 0.f};

    const unsigned short* a0p = &At[lm][lk];
    const unsigned short* a1p = &At[16 + lm][lk];
    const unsigned short* bp = Wb + (size_t)(n0 + lm) * EMB + lk;

#pragma unroll
    for (int k0 = 0; k0 < EMB; k0 += 32) {
        short8 a0 = *(const short8*)(a0p + k0);
        short8 a1 = *(const short8*)(a1p + k0);
        short8 b0 = *(const short8*)(bp + k0);
        short8 b1 = *(const short8*)(bp + 16 * EMB + k0);
        short8 b2 = *(const short8*)(bp + 32 * EMB + k0);
        short8 b3 = *(const short8*)(bp + 48 * EMB + k0);
        acc[0][0] = __builtin_amdgcn_mfma_f32_16x16x32_bf16(a0, b0, acc[0][0], 0, 0, 0);
        acc[0][1] = __builtin_amdgcn_mfma_f32_16x16x32_bf16(a0, b1, acc[0][1], 0, 0, 0);
        acc[0][2] = __builtin_amdgcn_mfma_f32_16x16x32_bf16(a0, b2, acc[0][2], 0, 0, 0);
        acc[0][3] = __builtin_amdgcn_mfma_f32_16x16x32_bf16(a0, b3, acc[0][3], 0, 0, 0);
        acc[1][0] = __builtin_amdgcn_mfma_f32_16x16x32_bf16(a1, b0, acc[1][0], 0, 0, 0);
        acc[1][1] = __builtin_amdgcn_mfma_f32_16x16x32_bf16(a1, b1, acc[1][1], 0, 0, 0);
        acc[1][2] = __builtin_amdgcn_mfma_f32_16x16x32_bf16(a1, b2, acc[1][2], 0, 0, 0);
        acc[1][3] = __builtin_amdgcn_mfma_f32_16x16x32_bf16(a1, b3, acc[1][3], 0, 0, 0);
    }

    // direct epilogue: per element read bf16(h) partner from At, store packed
#pragma unroll
    for (int mt = 0; mt < 2; ++mt)
#pragma unroll
        for (int nt = 0; nt < 4; ++nt) {
            int col = n0 + nt * 16 + lm;
#pragma unroll
            for (int r = 0; r < 4; ++r) {
                int row = mt * 16 + (l >> 4) * 4 + r;
                unsigned u = (unsigned)bf16r(__expf(acc[mt][nt][r])) |
                             ((unsigned)At[row][col] << 16);
                packed[(size_t)(m0 + row) * EMB + col] = u;
            }
        }
}

// ---------- merged independent work: gemm (blocks 0..624) | scatter ----------
// MFMA-bound gemm and atomic/latency-bound scatter fill each other's pipes
// instead of serializing as two underutilized dispatches.
__global__ __launch_bounds__(256) void scatter_gemm_kernel(
        const float* __restrict__ h, const unsigned short* __restrict__ Wb,
        unsigned int* __restrict__ packed, const int* __restrict__ src,
        const int* __restrict__ dst, int* __restrict__ cursor,
        int* __restrict__ csr_src) {
    if (blockIdx.x < GEMM_BLOCKS) {
        __shared__ unsigned short At[32][LDS_PITCH];
        gemm_tile(h, Wb, packed, At, blockIdx.x, threadIdx.x);
    } else {
        int i = (blockIdx.x - GEMM_BLOCKS) * 256 + threadIdx.x;
        if (i < N_EDGES) {
            int d = dst[i];
            int pos = atomicAdd(&cursor[d], 1);
            csr_src[pos] = src[i];
        }
    }
}

// ---------- aggregate: one wave per node, single pass ----------
#define PROC(p)                                                                  \
    {                                                                            \
        unsigned u;                                                              \
        float e, hv;                                                             \
        u = (p).x; e = __uint_as_float(u << 16);                                 \
        hv = __uint_as_float(u & 0xffff0000u); ss0 += e; a0 = fmaf(e, hv, a0);   \
        u = (p).y; e = __uint_as_float(u << 16);                                 \
        hv = __uint_as_float(u & 0xffff0000u); ss1 += e; a1 = fmaf(e, hv, a1);   \
        u = (p).z; e = __uint_as_float(u << 16);                                 \
        hv = __uint_as_float(u & 0xffff0000u); ss2 += e; a2 = fmaf(e, hv, a2);   \
        u = (p).w; e = __uint_as_float(u << 16);                                 \
        hv = __uint_as_float(u & 0xffff0000u); ss3 += e; a3 = fmaf(e, hv, a3);   \
    }

__global__ __launch_bounds__(256) void aggregate_kernel(
        const float* __restrict__ h, const uint4* __restrict__ packed,
        const int* __restrict__ row_start, const int* __restrict__ deg,
        const int* __restrict__ csr_src, float* __restrict__ out) {
    int w = threadIdx.x >> 6, l = threadIdx.x & 63;
    int node = blockIdx.x * 4 + w;
    int start = row_start[node];
    int d = deg[node];
    if (d == 0) {  // zero in-degree: pass through h
        float4 v = *(const float4*)(h + (size_t)node * EMB + l * 4);
        *(float4*)(out + (size_t)node * EMB + l * 4) = v;
        return;
    }
    int end = start + d;
    float ss0 = 0.f, ss1 = 0.f, ss2 = 0.f, ss3 = 0.f;
    float a0 = 0.f, a1 = 0.f, a2 = 0.f, a3 = 0.f;
    for (int base = start; base < end; base += 64) {
        int cnt = min(64, end - base);
        int sv = (l < cnt) ? csr_src[base + l] : 0;
        int i = 0;
        for (; i + 8 <= cnt; i += 8) {
            int s0 = __shfl(sv, i),     s1 = __shfl(sv, i + 1);
            int s2 = __shfl(sv, i + 2), s3 = __shfl(sv, i + 3);
            int s4 = __shfl(sv, i + 4), s5 = __shfl(sv, i + 5);
            int s6 = __shfl(sv, i + 6), s7 = __shfl(sv, i + 7);
            uint4 p0 = packed[(size_t)s0 * 64 + l];
            uint4 p1 = packed[(size_t)s1 * 64 + l];
            uint4 p2 = packed[(size_t)s2 * 64 + l];
            uint4 p3 = packed[(size_t)s3 * 64 + l];
            uint4 p4 = packed[(size_t)s4 * 64 + l];
            uint4 p5 = packed[(size_t)s5 * 64 + l];
            uint4 p6 = packed[(size_t)s6 * 64 + l];
            uint4 p7 = packed[(size_t)s7 * 64 + l];
            PROC(p0); PROC(p1); PROC(p2); PROC(p3);
            PROC(p4); PROC(p5); PROC(p6); PROC(p7);
        }
        // tail: wave-uniform predicated batch — all remaining loads in flight
        int r = cnt - i;
        if (r > 0) {
            int s0 = __shfl(sv, i);
            uint4 p0 = packed[(size_t)s0 * 64 + l];
            uint4 p1, p2, p3, p4, p5, p6;
            if (r > 1) { int s = __shfl(sv, i + 1); p1 = packed[(size_t)s * 64 + l]; }
            if (r > 2) { int s = __shfl(sv, i + 2); p2 = packed[(size_t)s * 64 + l]; }
            if (r > 3) { int s = __shfl(sv, i + 3); p3 = packed[(size_t)s * 64 + l]; }
            if (r > 4) { int s = __shfl(sv, i + 4); p4 = packed[(size_t)s * 64 + l]; }
            if (r > 5) { int s = __shfl(sv, i + 5); p5 = packed[(size_t)s * 64 + l]; }
            if (r > 6) { int s = __shfl(sv, i + 6); p6 = packed[(size_t)s * 64 + l]; }
            PROC(p0);
            if (r > 1) PROC(p1);
            if (r > 2) PROC(p2);
            if (r > 3) PROC(p3);
            if (r > 4) PROC(p4);
            if (r > 5) PROC(p5);
            if (r > 6) PROC(p6);
        }
    }
    float4 o;
    o.x = a0 / ss0; o.y = a1 / ss1; o.z = a2 / ss2; o.w = a3 / ss3;
    *(float4*)(out + (size_t)node * EMB + l * 4) = o;
}

// ---------- launch ----------
extern "C" void kernel_launch(void* const* d_in, const int* in_sizes, int n_in,
                              void* d_out, int out_size, void* d_ws, size_t ws_size,
                              hipStream_t stream) {
    const float* h      = (const float*)d_in[0];
    // W_nb (d_in[1]), b_nb (d_in[2]), b_self (d_in[4]) are mathematically
    // irrelevant: constant per (dst, channel) inside each softmax segment,
    // cancel exactly in alpha = e / seg_sum.
    const float* W_self = (const float*)d_in[3];
    const int*   src    = (const int*)d_in[5];
    const int*   dst    = (const int*)d_in[6];
    float* out = (float*)d_out;

    char* ws = (char*)d_ws;
    unsigned int* packed = (unsigned int*)ws;                 // [N,256] uint (E,h) pairs
    size_t off = (size_t)N_NODES * EMB * sizeof(unsigned int);
    unsigned short* Wb = (unsigned short*)(ws + off); off += (size_t)EMB * EMB * sizeof(unsigned short);
    int* deg       = (int*)(ws + off); off += (size_t)N_NODES * sizeof(int);
    int* total     = (int*)(ws + off); off += sizeof(int);
    int* row_start = (int*)(ws + off); off += (size_t)N_NODES * sizeof(int);
    int* cursor    = (int*)(ws + off); off += (size_t)N_NODES * sizeof(int);
    int* csr_src   = (int*)(ws + off); off += (size_t)N_EDGES * sizeof(int);

    // zeroes deg AND the adjacent total counter in one fill
    (void)hipMemsetAsync(deg, 0, (size_t)(N_NODES + 1) * sizeof(int), stream);

    prep_kernel<<<(N_EDGES + 255) / 256, 256, 0, stream>>>(W_self, dst, deg, Wb);
    alloc_kernel<<<(N_NODES + 255) / 256, 256, 0, stream>>>(deg, total, row_start, cursor);
    scatter_gemm_kernel<<<GEMM_BLOCKS + SCAT_BLOCKS, 256, 0, stream>>>(
        h, Wb, packed, src, dst, cursor, csr_src);
    aggregate_kernel<<<N_NODES / 4, 256, 0, stream>>>(h, (const uint4*)packed,
                                                      row_start, deg, csr_src, out);
}

// Round 4
// 153.827 us; speedup vs baseline: 2.8404x; 1.1413x over previous
//
#include <hip/hip_runtime.h>
#include <math.h>

#define N_NODES 20000
#define N_EDGES 320000
#define EMB 256
#define CAP 128                             // slots per node; max degree ~40 (12 sigma margin)
#define GEMM_BLOCKS (N_NODES / 32)          // 625
#define SCAT_BLOCKS ((N_EDGES + 255) / 256) // 1250
#define LDS_PITCH 264                       // 256 + 8 shorts: breaks bank-stride, keeps 16B align

typedef __attribute__((ext_vector_type(8))) short short8;
typedef __attribute__((ext_vector_type(4))) float floatx4;

__device__ __forceinline__ unsigned short bf16r(float x) {
    unsigned u = __float_as_uint(x);
    u += 0x7fffu + ((u >> 16) & 1u);
    return (unsigned short)(u >> 16);
}

// ---------- init: convert W_self to bf16 + zero slot counters ----------
// 79 blocks x 256 = 20224 threads: conv uses first 8192, zeroing covers 20000.
__global__ __launch_bounds__(256) void init_kernel(
        const float* __restrict__ W, unsigned short* __restrict__ Wb,
        int* __restrict__ cnt) {
    int gid = blockIdx.x * 256 + threadIdx.x;
    if (gid < N_NODES) cnt[gid] = 0;
    if (gid < (EMB * EMB) / 8) {
        long off = (long)gid * 8;
        float4 x = *(const float4*)(W + off);
        float4 y = *(const float4*)(W + off + 4);
        uint4 o;
        o.x = (unsigned)bf16r(x.x) | ((unsigned)bf16r(x.y) << 16);
        o.y = (unsigned)bf16r(x.z) | ((unsigned)bf16r(x.w) << 16);
        o.z = (unsigned)bf16r(y.x) | ((unsigned)bf16r(y.y) << 16);
        o.w = (unsigned)bf16r(y.z) | ((unsigned)bf16r(y.w) << 16);
        *(uint4*)(Wb + off) = o;
    }
}

// ---------------------------------------------------------------------------
// GEMM tile body: S = h @ W_self^T for 32 rows; packed[n][c] =
// (bf16(exp(S)), bf16(h)).  Direct epilogue from acc in C/D layout
// (col=lane&15, row=(lane>>4)*4+reg) — harness-verified in R2/R3.
// ---------------------------------------------------------------------------
__device__ __forceinline__ void gemm_tile(
        const float* __restrict__ h, const unsigned short* __restrict__ Wb,
        unsigned int* __restrict__ packed, unsigned short (*At)[LDS_PITCH],
        int b, int t) {
    int w = t >> 6, l = t & 63;
    int m0 = b * 32;
    int n0 = w * 64;
    int lm = l & 15, lk = (l >> 4) * 8;

    // stage A: 32 rows x 256 cols fp32 -> bf16 LDS, coalesced float4 reads
#pragma unroll
    for (int it = 0; it < 8; ++it) {
        int q = it * 256 + t;            // [0, 2048)
        int row = q >> 6;                // 64 float4 per row
        int c4 = (q & 63) * 4;
        float4 x = *(const float4*)(h + (size_t)(m0 + row) * EMB + c4);
        At[row][c4 + 0] = bf16r(x.x);
        At[row][c4 + 1] = bf16r(x.y);
        At[row][c4 + 2] = bf16r(x.z);
        At[row][c4 + 3] = bf16r(x.w);
    }
    __syncthreads();

    floatx4 acc[2][4];
#pragma unroll
    for (int mt = 0; mt < 2; ++mt)
#pragma unroll
        for (int nt = 0; nt < 4; ++nt) acc[mt][nt] = (floatx4){0.f, 0.f, 0.f, 0.f};

    const unsigned short* a0p = &At[lm][lk];
    const unsigned short* a1p = &At[16 + lm][lk];
    const unsigned short* bp = Wb + (size_t)(n0 + lm) * EMB + lk;

#pragma unroll
    for (int k0 = 0; k0 < EMB; k0 += 32) {
        short8 a0 = *(const short8*)(a0p + k0);
        short8 a1 = *(const short8*)(a1p + k0);
        short8 b0 = *(const short8*)(bp + k0);
        short8 b1 = *(const short8*)(bp + 16 * EMB + k0);
        short8 b2 = *(const short8*)(bp + 32 * EMB + k0);
        short8 b3 = *(const short8*)(bp + 48 * EMB + k0);
        acc[0][0] = __builtin_amdgcn_mfma_f32_16x16x32_bf16(a0, b0, acc[0][0], 0, 0, 0);
        acc[0][1] = __builtin_amdgcn_mfma_f32_16x16x32_bf16(a0, b1, acc[0][1], 0, 0, 0);
        acc[0][2] = __builtin_amdgcn_mfma_f32_16x16x32_bf16(a0, b2, acc[0][2], 0, 0, 0);
        acc[0][3] = __builtin_amdgcn_mfma_f32_16x16x32_bf16(a0, b3, acc[0][3], 0, 0, 0);
        acc[1][0] = __builtin_amdgcn_mfma_f32_16x16x32_bf16(a1, b0, acc[1][0], 0, 0, 0);
        acc[1][1] = __builtin_amdgcn_mfma_f32_16x16x32_bf16(a1, b1, acc[1][1], 0, 0, 0);
        acc[1][2] = __builtin_amdgcn_mfma_f32_16x16x32_bf16(a1, b2, acc[1][2], 0, 0, 0);
        acc[1][3] = __builtin_amdgcn_mfma_f32_16x16x32_bf16(a1, b3, acc[1][3], 0, 0, 0);
    }

    // direct epilogue: per element read bf16(h) partner from At, store packed
#pragma unroll
    for (int mt = 0; mt < 2; ++mt)
#pragma unroll
        for (int nt = 0; nt < 4; ++nt) {
            int col = n0 + nt * 16 + lm;
#pragma unroll
            for (int r = 0; r < 4; ++r) {
                int row = mt * 16 + (l >> 4) * 4 + r;
                unsigned u = (unsigned)bf16r(__expf(acc[mt][nt][r])) |
                             ((unsigned)At[row][col] << 16);
                packed[(size_t)(m0 + row) * EMB + col] = u;
            }
        }
}

// ---------- merged independent work: gemm (blocks 0..624) | bucket scatter ----------
// No CSR build needed: fixed-capacity buckets (CAP slots/node).  Scatter is a
// single atomic per edge; cnt doubles as the degree array for aggregate.
__global__ __launch_bounds__(256) void scatter_gemm_kernel(
        const float* __restrict__ h, const unsigned short* __restrict__ Wb,
        unsigned int* __restrict__ packed, const int* __restrict__ src,
        const int* __restrict__ dst, int* __restrict__ cnt,
        int* __restrict__ csr_src) {
    if (blockIdx.x < GEMM_BLOCKS) {
        __shared__ unsigned short At[32][LDS_PITCH];
        gemm_tile(h, Wb, packed, At, blockIdx.x, threadIdx.x);
    } else {
        int i = (blockIdx.x - GEMM_BLOCKS) * 256 + threadIdx.x;
        if (i < N_EDGES) {
            int d = dst[i];
            int slot = atomicAdd(&cnt[d], 1);
            slot = min(slot, CAP - 1);  // never OOB even on hypothetical overflow
            csr_src[(size_t)d * CAP + slot] = src[i];
        }
    }
}

// ---------- aggregate: one wave per node, single pass ----------
#define PROC(p)                                                                  \
    {                                                                            \
        unsigned u;                                                              \
        float e, hv;                                                             \
        u = (p).x; e = __uint_as_float(u << 16);                                 \
        hv = __uint_as_float(u & 0xffff0000u); ss0 += e; a0 = fmaf(e, hv, a0);   \
        u = (p).y; e = __uint_as_float(u << 16);                                 \
        hv = __uint_as_float(u & 0xffff0000u); ss1 += e; a1 = fmaf(e, hv, a1);   \
        u = (p).z; e = __uint_as_float(u << 16);                                 \
        hv = __uint_as_float(u & 0xffff0000u); ss2 += e; a2 = fmaf(e, hv, a2);   \
        u = (p).w; e = __uint_as_float(u << 16);                                 \
        hv = __uint_as_float(u & 0xffff0000u); ss3 += e; a3 = fmaf(e, hv, a3);   \
    }

__global__ __launch_bounds__(256) void aggregate_kernel(
        const float* __restrict__ h, const uint4* __restrict__ packed,
        const int* __restrict__ cnt, const int* __restrict__ csr_src,
        float* __restrict__ out) {
    int w = threadIdx.x >> 6, l = threadIdx.x & 63;
    int node = blockIdx.x * 4 + w;
    int d = min(cnt[node], CAP);
    if (d == 0) {  // zero in-degree: pass through h
        float4 v = *(const float4*)(h + (size_t)node * EMB + l * 4);
        *(float4*)(out + (size_t)node * EMB + l * 4) = v;
        return;
    }
    const int* seg = csr_src + (size_t)node * CAP;
    float ss0 = 0.f, ss1 = 0.f, ss2 = 0.f, ss3 = 0.f;
    float a0 = 0.f, a1 = 0.f, a2 = 0.f, a3 = 0.f;
    for (int base = 0; base < d; base += 64) {
        int cnt64 = min(64, d - base);
        int sv = (l < cnt64) ? seg[base + l] : 0;
        int i = 0;
        for (; i + 8 <= cnt64; i += 8) {
            int s0 = __shfl(sv, i),     s1 = __shfl(sv, i + 1);
            int s2 = __shfl(sv, i + 2), s3 = __shfl(sv, i + 3);
            int s4 = __shfl(sv, i + 4), s5 = __shfl(sv, i + 5);
            int s6 = __shfl(sv, i + 6), s7 = __shfl(sv, i + 7);
            uint4 p0 = packed[(size_t)s0 * 64 + l];
            uint4 p1 = packed[(size_t)s1 * 64 + l];
            uint4 p2 = packed[(size_t)s2 * 64 + l];
            uint4 p3 = packed[(size_t)s3 * 64 + l];
            uint4 p4 = packed[(size_t)s4 * 64 + l];
            uint4 p5 = packed[(size_t)s5 * 64 + l];
            uint4 p6 = packed[(size_t)s6 * 64 + l];
            uint4 p7 = packed[(size_t)s7 * 64 + l];
            PROC(p0); PROC(p1); PROC(p2); PROC(p3);
            PROC(p4); PROC(p5); PROC(p6); PROC(p7);
        }
        // tail: wave-uniform predicated batch — all remaining loads in flight
        int r = cnt64 - i;
        if (r > 0) {
            int s0 = __shfl(sv, i);
            uint4 p0 = packed[(size_t)s0 * 64 + l];
            uint4 p1, p2, p3, p4, p5, p6;
            if (r > 1) { int s = __shfl(sv, i + 1); p1 = packed[(size_t)s * 64 + l]; }
            if (r > 2) { int s = __shfl(sv, i + 2); p2 = packed[(size_t)s * 64 + l]; }
            if (r > 3) { int s = __shfl(sv, i + 3); p3 = packed[(size_t)s * 64 + l]; }
            if (r > 4) { int s = __shfl(sv, i + 4); p4 = packed[(size_t)s * 64 + l]; }
            if (r > 5) { int s = __shfl(sv, i + 5); p5 = packed[(size_t)s * 64 + l]; }
            if (r > 6) { int s = __shfl(sv, i + 6); p6 = packed[(size_t)s * 64 + l]; }
            PROC(p0);
            if (r > 1) PROC(p1);
            if (r > 2) PROC(p2);
            if (r > 3) PROC(p3);
            if (r > 4) PROC(p4);
            if (r > 5) PROC(p5);
            if (r > 6) PROC(p6);
        }
    }
    float4 o;
    o.x = a0 / ss0; o.y = a1 / ss1; o.z = a2 / ss2; o.w = a3 / ss3;
    *(float4*)(out + (size_t)node * EMB + l * 4) = o;
}

// ---------- launch ----------
extern "C" void kernel_launch(void* const* d_in, const int* in_sizes, int n_in,
                              void* d_out, int out_size, void* d_ws, size_t ws_size,
                              hipStream_t stream) {
    const float* h      = (const float*)d_in[0];
    // W_nb (d_in[1]), b_nb (d_in[2]), b_self (d_in[4]) are mathematically
    // irrelevant: constant per (dst, channel) inside each softmax segment,
    // cancel exactly in alpha = e / seg_sum.
    const float* W_self = (const float*)d_in[3];
    const int*   src    = (const int*)d_in[5];
    const int*   dst    = (const int*)d_in[6];
    float* out = (float*)d_out;

    char* ws = (char*)d_ws;
    unsigned int* packed = (unsigned int*)ws;                 // [N,256] uint (E,h) pairs
    size_t off = (size_t)N_NODES * EMB * sizeof(unsigned int);
    unsigned short* Wb = (unsigned short*)(ws + off); off += (size_t)EMB * EMB * sizeof(unsigned short);
    int* cnt     = (int*)(ws + off); off += (size_t)N_NODES * sizeof(int);
    int* csr_src = (int*)(ws + off); off += (size_t)N_NODES * CAP * sizeof(int);

    init_kernel<<<(N_NODES + 255) / 256, 256, 0, stream>>>(W_self, Wb, cnt);
    scatter_gemm_kernel<<<GEMM_BLOCKS + SCAT_BLOCKS, 256, 0, stream>>>(
        h, Wb, packed, src, dst, cnt, csr_src);
    aggregate_kernel<<<N_NODES / 4, 256, 0, stream>>>(h, (const uint4*)packed,
                                                      cnt, csr_src, out);
}